// Round 1
// baseline (169.296 us; speedup 1.0000x reference)
//
#include <hip/hip_runtime.h>
#include <hip/hip_bf16.h>
#include <stdint.h>

#define BATCH 8192
#define DIM   512
#define TILE  128
#define BK    32

typedef __attribute__((ext_vector_type(8))) short short8;
typedef __attribute__((ext_vector_type(4))) float f32x4;

// async global->LDS, 16B per lane, dest = wave-uniform base + lane*16
__device__ __forceinline__ void gld_lds16(const void* g, void* l) {
  __builtin_amdgcn_global_load_lds(
      (__attribute__((address_space(1))) void*)(uintptr_t)g,
      (__attribute__((address_space(3))) void*)(uintptr_t)l,
      16, 0, 0);
}

// ---------------------------------------------------------------------------
// Kernel 1: row-normalize fp32 features -> bf16, also zero rowsum accumulator
// ---------------------------------------------------------------------------
__global__ __launch_bounds__(256) void normalize_bf16(
    const float* __restrict__ x, __hip_bfloat16* __restrict__ o,
    float* __restrict__ rowsum) {
  const int row = blockIdx.x;
  if (threadIdx.x == 0) rowsum[row] = 0.0f;
  const float2* xr = (const float2*)(x + (size_t)row * DIM);
  float2 v = xr[threadIdx.x];          // 256 threads * 2 floats = 512
  float ss = v.x * v.x + v.y * v.y;
#pragma unroll
  for (int m = 32; m > 0; m >>= 1) ss += __shfl_xor(ss, m, 64);
  __shared__ float ws[4];
  const int lane = threadIdx.x & 63, wv = threadIdx.x >> 6;
  if (lane == 0) ws[wv] = ss;
  __syncthreads();
  const float tot = ws[0] + ws[1] + ws[2] + ws[3];
  const float inv = 1.0f / fmaxf(sqrtf(tot), 1e-12f);
  __hip_bfloat162 r;
  r.x = __float2bfloat16(v.x * inv);
  r.y = __float2bfloat16(v.y * inv);
  ((__hip_bfloat162*)(o + (size_t)row * DIM))[threadIdx.x] = r;
}

// ---------------------------------------------------------------------------
// Kernel 2: 128x128 bf16 MFMA tile of sim = F*F^T / T, fused exp-rowsum
// epilogue (diag masked), positive-pair sim extraction.
// 4 waves in 2x2, each wave 64x64 via 4x4 of 16x16x32 MFMAs, BK=32.
// LDS layout: A tile [128][32] bf16 row-major (64B rows), then B tile.
// 16B-block XOR swizzle: LDS[R][b] holds logical k-block b ^ ((R>>1)&3)
// -> ds_read_b128 fragment reads are 2-way (free) per 16-lane phase.
// ---------------------------------------------------------------------------
__global__ __launch_bounds__(256) void sim_lse_kernel(
    const __hip_bfloat16* __restrict__ F, float* __restrict__ rowsum,
    float* __restrict__ possim) {
  __shared__ __hip_bfloat16 smem[2 * TILE * BK];  // 16 KB (A: 0..8191B, B: 8192..16383B)
  __shared__ float rowAcc[TILE];

  const int tid   = threadIdx.x;
  const int lane  = tid & 63;
  const int wv    = tid >> 6;
  const int waveM = wv >> 1;
  const int waveN = wv & 1;
  const int quad  = lane >> 4;
  const int l15   = lane & 15;

  const int rowBase = blockIdx.y * TILE;
  const int colBase = blockIdx.x * TILE;

  if (tid < TILE) rowAcc[tid] = 0.0f;

  f32x4 acc[4][4] = {};

  // --- staging geometry: each wave stages 2 chunks (16 rows each) of A and B.
  // chunk byte layout: lane -> row (lane>>2), 16B slot (lane&3)
  const int sRow0 = wv * 32 + (lane >> 2);
  const int sRow1 = sRow0 + 16;
  const int sb    = lane & 3;
  const int g0 = sb ^ ((sRow0 >> 1) & 3);   // logical k-block to fetch (swizzle)
  const int g1 = sb ^ ((sRow1 >> 1) & 3);

  const __hip_bfloat16* gA0 = F + (size_t)(rowBase + sRow0) * DIM + g0 * 8;
  const __hip_bfloat16* gA1 = F + (size_t)(rowBase + sRow1) * DIM + g1 * 8;
  const __hip_bfloat16* gB0 = F + (size_t)(colBase + sRow0) * DIM + g0 * 8;
  const __hip_bfloat16* gB1 = F + (size_t)(colBase + sRow1) * DIM + g1 * 8;

  char* ldsA0 = (char*)smem + (wv * 2 + 0) * 1024;
  char* ldsA1 = (char*)smem + (wv * 2 + 1) * 1024;
  char* ldsB0 = (char*)smem + 8192 + (wv * 2 + 0) * 1024;
  char* ldsB1 = (char*)smem + 8192 + (wv * 2 + 1) * 1024;

  // --- fragment read addresses (fixed across k iters); undo the swizzle
  const char* aAddr[4];
  const char* bAddr[4];
#pragma unroll
  for (int i = 0; i < 4; ++i) {
    const int Ra = waveM * 64 + i * 16 + l15;
    aAddr[i] = (char*)smem + Ra * 64 + (quad ^ ((Ra >> 1) & 3)) * 16;
    const int Rb = waveN * 64 + i * 16 + l15;
    bAddr[i] = (char*)smem + 8192 + Rb * 64 + (quad ^ ((Rb >> 1) & 3)) * 16;
  }

  for (int k0 = 0; k0 < DIM; k0 += BK) {
    gld_lds16(gA0 + k0, ldsA0);
    gld_lds16(gA1 + k0, ldsA1);
    gld_lds16(gB0 + k0, ldsB0);
    gld_lds16(gB1 + k0, ldsB1);
    __syncthreads();   // compiler drains vmcnt before s_barrier

    short8 a[4], b[4];
#pragma unroll
    for (int i = 0; i < 4; ++i) {
      a[i] = *(const short8*)aAddr[i];
      b[i] = *(const short8*)bAddr[i];
    }
#pragma unroll
    for (int mi = 0; mi < 4; ++mi)
#pragma unroll
      for (int ni = 0; ni < 4; ++ni)
        acc[mi][ni] =
            __builtin_amdgcn_mfma_f32_16x16x32_bf16(a[mi], b[ni], acc[mi][ni], 0, 0, 0);
    __syncthreads();
  }

  // --- epilogue: sim = acc/T; mask diag; exp; row-sum; positive extraction
  const float invT = 1.0f / 0.07f;
#pragma unroll
  for (int mi = 0; mi < 4; ++mi) {
#pragma unroll
    for (int r = 0; r < 4; ++r) {
      const int lrow = waveM * 64 + mi * 16 + quad * 4 + r;   // tile-local row
      const int gi = rowBase + lrow;
      const int pj = (gi + 4096) & 8191;
      float s0 = 0.0f;
#pragma unroll
      for (int ni = 0; ni < 4; ++ni) {
        const int gj = colBase + waveN * 64 + ni * 16 + l15;
        const float s = acc[mi][ni][r] * invT;
        if (gj == pj) possim[gi] = s;                // unique writer
        s0 += (gj == gi) ? 0.0f : __expf(s);
      }
      // reduce across the 16 lanes of this quad (columns of the wave)
#pragma unroll
      for (int m = 1; m < 16; m <<= 1) s0 += __shfl_xor(s0, m, 64);
      if (l15 == 0) atomicAdd(&rowAcc[lrow], s0);
    }
  }
  __syncthreads();
  if (tid < TILE) atomicAdd(&rowsum[rowBase + tid], rowAcc[tid]);
}

// ---------------------------------------------------------------------------
// Kernel 3: loss = mean_i( log(rowsum_i) - possim_i )
// ---------------------------------------------------------------------------
__global__ __launch_bounds__(256) void finalize_kernel(
    const float* __restrict__ rowsum, const float* __restrict__ possim,
    float* __restrict__ out) {
  float acc = 0.0f;
  for (int i = threadIdx.x; i < BATCH; i += 256)
    acc += logf(rowsum[i]) - possim[i];
#pragma unroll
  for (int m = 32; m > 0; m >>= 1) acc += __shfl_xor(acc, m, 64);
  __shared__ float ws[4];
  const int lane = threadIdx.x & 63, wv = threadIdx.x >> 6;
  if (lane == 0) ws[wv] = acc;
  __syncthreads();
  if (threadIdx.x == 0)
    out[0] = (ws[0] + ws[1] + ws[2] + ws[3]) * (1.0f / (float)BATCH);
}

extern "C" void kernel_launch(void* const* d_in, const int* in_sizes, int n_in,
                              void* d_out, int out_size, void* d_ws, size_t ws_size,
                              hipStream_t stream) {
  const float* x = (const float*)d_in[0];
  float* out = (float*)d_out;

  // ws layout: [0, 8 MB) bf16 normalized features; then rowsum[8192]; possim[8192]
  __hip_bfloat16* Fb = (__hip_bfloat16*)d_ws;
  float* rowsum = (float*)((char*)d_ws + (size_t)BATCH * DIM * sizeof(__hip_bfloat16));
  float* possim = rowsum + BATCH;

  normalize_bf16<<<BATCH, 256, 0, stream>>>(x, Fb, rowsum);
  dim3 grid(BATCH / TILE, BATCH / TILE);
  sim_lse_kernel<<<grid, 256, 0, stream>>>(Fb, rowsum, possim);
  finalize_kernel<<<1, 256, 0, stream>>>(rowsum, possim, out);
}

// Round 2
// 126.354 us; speedup vs baseline: 1.3399x; 1.3399x over previous
//
#include <hip/hip_runtime.h>
#include <hip/hip_bf16.h>
#include <stdint.h>

#define BATCH 8192
#define DIM   512
#define TILE  128
#define BK    64
#define NT    (BATCH / TILE)          // 64 tiles per dim
#define NPAIR (NT * (NT + 1) / 2)     // 2080 upper-triangle tile pairs

typedef __attribute__((ext_vector_type(8))) short short8;
typedef __attribute__((ext_vector_type(4))) float f32x4;

// async global->LDS, 16B per lane, dest = wave-uniform base + lane*16
__device__ __forceinline__ void gld_lds16(const void* g, void* l) {
  __builtin_amdgcn_global_load_lds(
      (__attribute__((address_space(1))) void*)(uintptr_t)g,
      (__attribute__((address_space(3))) void*)(uintptr_t)l,
      16, 0, 0);
}

// ---------------------------------------------------------------------------
// Kernel 1: row-normalize fp32 -> bf16. One wave per row, no barriers.
// lane reads 2 float4 (8 floats), writes 2 ushort4 (8 bf16). Zeroes rowsum.
// ---------------------------------------------------------------------------
__global__ __launch_bounds__(256) void normalize_bf16(
    const float* __restrict__ x, __hip_bfloat16* __restrict__ o,
    float* __restrict__ rowsum) {
  const int wv = threadIdx.x >> 6, lane = threadIdx.x & 63;
  const int row = blockIdx.x * 4 + wv;
  if (lane == 0) rowsum[row] = 0.0f;
  const float4* xr = (const float4*)(x + (size_t)row * DIM);
  const float4 v0 = xr[lane];
  const float4 v1 = xr[lane + 64];
  float ss = v0.x * v0.x + v0.y * v0.y + v0.z * v0.z + v0.w * v0.w +
             v1.x * v1.x + v1.y * v1.y + v1.z * v1.z + v1.w * v1.w;
#pragma unroll
  for (int m = 32; m > 0; m >>= 1) ss += __shfl_xor(ss, m, 64);
  const float inv = 1.0f / fmaxf(sqrtf(ss), 1e-12f);
  ushort4 p0, p1;
  p0.x = __bfloat16_as_ushort(__float2bfloat16(v0.x * inv));
  p0.y = __bfloat16_as_ushort(__float2bfloat16(v0.y * inv));
  p0.z = __bfloat16_as_ushort(__float2bfloat16(v0.z * inv));
  p0.w = __bfloat16_as_ushort(__float2bfloat16(v0.w * inv));
  p1.x = __bfloat16_as_ushort(__float2bfloat16(v1.x * inv));
  p1.y = __bfloat16_as_ushort(__float2bfloat16(v1.y * inv));
  p1.z = __bfloat16_as_ushort(__float2bfloat16(v1.z * inv));
  p1.w = __bfloat16_as_ushort(__float2bfloat16(v1.w * inv));
  ushort4* orow = (ushort4*)(o + (size_t)row * DIM);
  orow[lane]      = p0;
  orow[lane + 64] = p1;
}

// ---------------------------------------------------------------------------
// Kernel 2: symmetric-aware 128x128 bf16 MFMA tiles of sim = F*F^T / T.
// Only upper-triangle tile pairs (by <= bx); off-diagonal tiles credit both
// row sums (rows of tile by) and column sums (rows of tile bx, by symmetry).
// BK=64: 8 K-iterations, 32 MFMA per barrier-pair.
// LDS: row stride 128B, 8x16B blocks, XOR swizzle phys = b ^ (R&7)
// -> ds_read_b128 is 2-way bank aliased (free). gld dest = base + lane*16
// matches row=(lane>>3), block=(lane&7) exactly.
// ---------------------------------------------------------------------------
__global__ __launch_bounds__(256, 4) void sim_lse_kernel(
    const __hip_bfloat16* __restrict__ F, float* __restrict__ rowsum,
    float* __restrict__ possim) {
  __shared__ __hip_bfloat16 smem[2 * TILE * BK];  // 32 KB: A [0,16K), B [16K,32K)
  __shared__ float rowAcc[TILE];
  __shared__ float colAcc[TILE];

  // --- decode linear block id -> upper-triangle (by, bx), by <= bx
  const int t = blockIdx.x;
  int by = (int)((129.0f - sqrtf(129.0f * 129.0f - 8.0f * (float)t)) * 0.5f);
  if (by > NT - 1) by = NT - 1;
  if (by < 0) by = 0;
  while ((by + 1) * (129 - (by + 1)) / 2 <= t) ++by;
  while (by * (129 - by) / 2 > t) --by;
  const int bx = by + (t - by * (129 - by) / 2);
  const bool diagTile = (bx == by);

  const int rowBase = by * TILE;
  const int colBase = bx * TILE;

  const int tid   = threadIdx.x;
  const int lane  = tid & 63;
  const int wv    = tid >> 6;
  const int waveM = wv >> 1;
  const int waveN = wv & 1;
  const int quad  = lane >> 4;
  const int l15   = lane & 15;

  if (tid < TILE) { rowAcc[tid] = 0.0f; colAcc[tid] = 0.0f; }

  f32x4 acc[4][4] = {};

  // --- staging: tile = 16 chunks of 8 rows (1 KB each); wave wv stages
  // chunks [4wv, 4wv+4) of A and of B.
  const int sb = lane & 7;                       // physical 16B slot in row
  const __hip_bfloat16* gA[4];
  const __hip_bfloat16* gB[4];
  char* ldsA[4];
  char* ldsB[4];
#pragma unroll
  for (int c = 0; c < 4; ++c) {
    const int sRow = wv * 32 + c * 8 + (lane >> 3);
    const int g = sb ^ (sRow & 7);               // logical k-block fetched
    gA[c] = F + (size_t)(rowBase + sRow) * DIM + g * 8;
    gB[c] = F + (size_t)(colBase + sRow) * DIM + g * 8;
    ldsA[c] = (char*)smem + (wv * 4 + c) * 1024;
    ldsB[c] = (char*)smem + 16384 + (wv * 4 + c) * 1024;
  }

  // --- fragment LDS offsets (ks=0); ks=32 address = offset ^ 64
  int aOff[4], bOff[4];
#pragma unroll
  for (int i = 0; i < 4; ++i) {
    const int Ra = waveM * 64 + i * 16 + l15;
    aOff[i] = Ra * 128 + (quad ^ (Ra & 7)) * 16;
    const int Rb = waveN * 64 + i * 16 + l15;
    bOff[i] = 16384 + Rb * 128 + (quad ^ (Rb & 7)) * 16;
  }
  char* sbase = (char*)smem;

  for (int k0 = 0; k0 < DIM; k0 += BK) {
#pragma unroll
    for (int c = 0; c < 4; ++c) {
      gld_lds16(gA[c] + k0, ldsA[c]);
      gld_lds16(gB[c] + k0, ldsB[c]);
    }
    __syncthreads();

    short8 a[4], b[4];
#pragma unroll
    for (int i = 0; i < 4; ++i) {
      a[i] = *(const short8*)(sbase + aOff[i]);
      b[i] = *(const short8*)(sbase + bOff[i]);
    }
#pragma unroll
    for (int mi = 0; mi < 4; ++mi)
#pragma unroll
      for (int ni = 0; ni < 4; ++ni)
        acc[mi][ni] =
            __builtin_amdgcn_mfma_f32_16x16x32_bf16(a[mi], b[ni], acc[mi][ni], 0, 0, 0);
#pragma unroll
    for (int i = 0; i < 4; ++i) {
      a[i] = *(const short8*)(sbase + (aOff[i] ^ 64));
      b[i] = *(const short8*)(sbase + (bOff[i] ^ 64));
    }
#pragma unroll
    for (int mi = 0; mi < 4; ++mi)
#pragma unroll
      for (int ni = 0; ni < 4; ++ni)
        acc[mi][ni] =
            __builtin_amdgcn_mfma_f32_16x16x32_bf16(a[mi], b[ni], acc[mi][ni], 0, 0, 0);
    __syncthreads();
  }

  // --- epilogue: s = acc/T; e = exp(s) (diag masked); row sums always,
  // col sums + dual possim write for off-diagonal tiles.
  const float invT = 1.0f / 0.07f;
  float colpart[4] = {0.0f, 0.0f, 0.0f, 0.0f};
#pragma unroll
  for (int mi = 0; mi < 4; ++mi) {
#pragma unroll
    for (int r = 0; r < 4; ++r) {
      const int lrow = waveM * 64 + mi * 16 + quad * 4 + r;
      const int gi = rowBase + lrow;
      const int pj = (gi + 4096) & 8191;
      float rsum = 0.0f;
#pragma unroll
      for (int ni = 0; ni < 4; ++ni) {
        const int gj = colBase + waveN * 64 + ni * 16 + l15;
        const float s = acc[mi][ni][r] * invT;
        if (!diagTile && gj == pj) { possim[gi] = s; possim[gj] = s; }
        const float e = (gi == gj) ? 0.0f : __expf(s);
        rsum += e;
        colpart[ni] += e;
      }
#pragma unroll
      for (int m = 1; m < 16; m <<= 1) rsum += __shfl_xor(rsum, m, 64);
      if (l15 == 0) atomicAdd(&rowAcc[lrow], rsum);
    }
  }
  if (!diagTile) {
#pragma unroll
    for (int ni = 0; ni < 4; ++ni) {
      float c = colpart[ni];
      c += __shfl_xor(c, 16, 64);
      c += __shfl_xor(c, 32, 64);
      if (quad == 0) atomicAdd(&colAcc[waveN * 64 + ni * 16 + l15], c);
    }
  }
  __syncthreads();
  if (tid < TILE) {
    atomicAdd(&rowsum[rowBase + tid], rowAcc[tid]);
    if (!diagTile) atomicAdd(&rowsum[colBase + tid], colAcc[tid]);
  }
}

// ---------------------------------------------------------------------------
// Kernel 3: loss = mean_i( log(rowsum_i) - possim_i )
// ---------------------------------------------------------------------------
__global__ __launch_bounds__(256) void finalize_kernel(
    const float* __restrict__ rowsum, const float* __restrict__ possim,
    float* __restrict__ out) {
  float acc = 0.0f;
  for (int i = threadIdx.x; i < BATCH; i += 256)
    acc += logf(rowsum[i]) - possim[i];
#pragma unroll
  for (int m = 32; m > 0; m >>= 1) acc += __shfl_xor(acc, m, 64);
  __shared__ float ws[4];
  const int lane = threadIdx.x & 63, wv = threadIdx.x >> 6;
  if (lane == 0) ws[wv] = acc;
  __syncthreads();
  if (threadIdx.x == 0)
    out[0] = (ws[0] + ws[1] + ws[2] + ws[3]) * (1.0f / (float)BATCH);
}

extern "C" void kernel_launch(void* const* d_in, const int* in_sizes, int n_in,
                              void* d_out, int out_size, void* d_ws, size_t ws_size,
                              hipStream_t stream) {
  const float* x = (const float*)d_in[0];
  float* out = (float*)d_out;

  __hip_bfloat16* Fb = (__hip_bfloat16*)d_ws;
  float* rowsum = (float*)((char*)d_ws + (size_t)BATCH * DIM * sizeof(__hip_bfloat16));
  float* possim = rowsum + BATCH;

  normalize_bf16<<<BATCH / 4, 256, 0, stream>>>(x, Fb, rowsum);
  sim_lse_kernel<<<NPAIR, 256, 0, stream>>>(Fb, rowsum, possim);
  finalize_kernel<<<1, 256, 0, stream>>>(rowsum, possim, out);
}